// Round 9
// baseline (162.015 us; speedup 1.0000x reference)
//
#include <hip/hip_runtime.h>
#include <math.h>

// Problem constants (fixed by setup_inputs): B=4096, T=512, Q=4
#define T_DIM 512
#define GAMMA_F 0.997f
#define EPS_F 1e-3f
// log2(0.997)
#define LOG2_GAMMA (-0.0043345907f)

typedef float v4f __attribute__((ext_vector_type(4)));

__device__ __forceinline__ float inv_rescale_f(float x) {
    float s = (x > 0.f) ? 1.f : ((x < 0.f) ? -1.f : 0.f);
    float sqrt_arg = 1.f + 4.f * EPS_F * (fabsf(x) + 1.f + EPS_F);
    float q = (sqrtf(sqrt_arg) - 1.f) * (1.f / (2.f * EPS_F));
    return s * (q * q - 1.f);
}

__device__ __forceinline__ float rescale_f(float x) {
    return copysignf(sqrtf(fabsf(x) + 1.f) - 1.f, x) + EPS_F * x;
}

// Wave-overlap decomposition: each 64-lane wave produces 60 outputs (lanes
// 60-63 are halo suppliers only). Window taps come from __shfl_down — zero
// tap loads, zero LDS, zero barrier. Validity weights (t+k >= T => w=0)
// also neutralize any cross-row shuffle garbage, and the next-term's clamped
// m*(1-d) is loaded directly, so row straddling inside a wave is safe.
// Each thread handles 2 elements (rows b, b+B/2) for ILP. Per-thread VMEM:
// 16 loads + 2 stores, zero redundancy.
__global__ __launch_bounds__(256) void nstep_qloss_kernel(
    const float* __restrict__ cur_q,    // (B,T,4)
    const float* __restrict__ next_q,   // (B,T,4)
    const float* __restrict__ log_p,    // (B,T)
    const float* __restrict__ reward,   // (B,T,4)
    const float* __restrict__ is_done,  // (B,T)
    const float* __restrict__ mask,     // (B,T)
    float* __restrict__ out,            // (B,T,4)
    int HALF)                           // B*T/2
{
    int lane = threadIdx.x & 63;
    int gw   = (blockIdx.x * 256 + threadIdx.x) >> 6;   // global wave id
    int idx  = gw * 60 + lane;                          // output idx, set A
    int lidx = (idx < HALF) ? idx : (HALF - 1);         // clamped load idx
    bool outv = (lane < 60) && (idx < HALF);

    int t    = lidx & (T_DIM - 1);
    int base = lidx - t;
    int t4   = (t + 4 < T_DIM) ? (t + 4) : (T_DIM - 1);
    int o4   = base + t4;
    int lidx2 = lidx + HALF;                            // set B (row b + B/2)
    int o42   = o4 + HALF;

    const v4f* rew4 = (const v4f*)reward;
    const v4f* nq4  = (const v4f*)next_q;
    const v4f* cq4  = (const v4f*)cur_q;
    v4f* out4       = (v4f*)out;

    // ---- all 16 loads up front, independent ----
    float mA = mask[lidx], dA = is_done[lidx], pA = log_p[lidx];
    v4f   rA = rew4[lidx];
    float m4A = mask[o4], d4A = is_done[o4];
    v4f   nqA = nq4[o4], cqA = cq4[lidx];

    float mB = mask[lidx2], dB = is_done[lidx2], pB = log_p[lidx2];
    v4f   rB = rew4[lidx2];
    float m4B = mask[o42], d4B = is_done[o42];
    v4f   nqB = nq4[o42], cqB = cq4[lidx2];

    // ---- shuffle payloads: pre-masked ----
    float LA = mA * (1.f - dA) * pA;       // m*(1-d)*log_p
    float xA = mA * rA.x, yA = mA * rA.y, zA = mA * rA.z, wA = mA * rA.w;
    float LB = mB * (1.f - dB) * pB;
    float xB = mB * rB.x, yB = mB * rB.y, zB = mB * rB.z, wB = mB * rB.w;

    // ---- weights (shared by both sets: same t) ----
    const float g1 = GAMMA_F;
    const float g2 = g1 * g1;
    const float g3 = g2 * g1;
    const float g4 = g2 * g2;
    float wk[4];
    wk[0] = ((t + 1 < T_DIM) ? 1.f : 0.f) * g1;
    wk[1] = ((t + 2 < T_DIM) ? 1.f : 0.f) * g2;
    wk[2] = ((t + 3 < T_DIM) ? 1.f : 0.f) * g3;
    wk[3] = ((t + 4 < T_DIM) ? 1.f : 0.f) * g4;
    float coeff = exp2f((float)t4 * LOG2_GAMMA);   // gamma^i, absolute idx (faithful)

    // ---- window sums via cross-lane shuffles (tap 0 = own) ----
    float aA0 = xA, aA1 = yA, aA2 = zA, aA3 = wA, LsA = LA;
    float aB0 = xB, aB1 = yB, aB2 = zB, aB3 = wB, LsB = LB;
#pragma unroll
    for (int k = 1; k <= 4; ++k) {
        float w = wk[k - 1];
        aA0 = fmaf(w, __shfl_down(xA, k), aA0);
        aA1 = fmaf(w, __shfl_down(yA, k), aA1);
        aA2 = fmaf(w, __shfl_down(zA, k), aA2);
        aA3 = fmaf(w, __shfl_down(wA, k), aA3);
        LsA = fmaf(w, __shfl_down(LA, k), LsA);
        aB0 = fmaf(w, __shfl_down(xB, k), aB0);
        aB1 = fmaf(w, __shfl_down(yB, k), aB1);
        aB2 = fmaf(w, __shfl_down(zB, k), aB2);
        aB3 = fmaf(w, __shfl_down(wB, k), aB3);
        LsB = fmaf(w, __shfl_down(LB, k), LsB);
    }
    LsA *= GAMMA_F * (1.f / 3.f);          // extra gamma factor * inv_num_q
    LsB *= GAMMA_F * (1.f / 3.f);

    // ---- epilogue, set A ----
    {
        float g = coeff * m4A * (1.f - d4A);
        float nt0 = g * inv_rescale_f(nqA.x);
        float nt1 = g * inv_rescale_f(nqA.y);
        float nt2 = g * inv_rescale_f(nqA.z);
        float nt3 = g * inv_rescale_f(nqA.w);
        // q_w = {1, 0.5, 0, 2}; inv_qw = {1, 2, 0, 0.5}
        float tgt0 = rescale_f(aA0 + nt0 + 1.0f * LsA);
        float tgt1 = rescale_f(aA1 + nt1 + 2.0f * LsA);
        float tgt2 = rescale_f(aA2 + nt2);
        float tgt3 = rescale_f(aA3 + nt3 + 0.5f * LsA);
        (void)tgt2;
        float hm = 0.5f * mA;
        float e0 = cqA.x - tgt0;
        float e1 = cqA.y - tgt1;
        float e3 = cqA.w - tgt3;
        v4f o;
        o.x = hm * e0 * e0;
        o.y = hm * 0.5f * e1 * e1;
        o.z = 0.f;                          // q_w[2] == 0
        o.w = hm * 2.0f * e3 * e3;
        if (outv) out4[idx] = o;
    }
    // ---- epilogue, set B ----
    {
        float g = coeff * m4B * (1.f - d4B);
        float nt0 = g * inv_rescale_f(nqB.x);
        float nt1 = g * inv_rescale_f(nqB.y);
        float nt2 = g * inv_rescale_f(nqB.z);
        float nt3 = g * inv_rescale_f(nqB.w);
        float tgt0 = rescale_f(aB0 + nt0 + 1.0f * LsB);
        float tgt1 = rescale_f(aB1 + nt1 + 2.0f * LsB);
        float tgt2 = rescale_f(aB2 + nt2);
        float tgt3 = rescale_f(aB3 + nt3 + 0.5f * LsB);
        (void)tgt2;
        float hm = 0.5f * mB;
        float e0 = cqB.x - tgt0;
        float e1 = cqB.y - tgt1;
        float e3 = cqB.w - tgt3;
        v4f o;
        o.x = hm * e0 * e0;
        o.y = hm * 0.5f * e1 * e1;
        o.z = 0.f;
        o.w = hm * 2.0f * e3 * e3;
        if (outv) out4[idx + HALF] = o;
    }
}

extern "C" void kernel_launch(void* const* d_in, const int* in_sizes, int n_in,
                              void* d_out, int out_size, void* d_ws, size_t ws_size,
                              hipStream_t stream) {
    const float* cur_q   = (const float*)d_in[0];
    const float* next_q  = (const float*)d_in[1];
    const float* log_p   = (const float*)d_in[2];
    const float* reward  = (const float*)d_in[3];
    const float* is_done = (const float*)d_in[4];
    const float* mask    = (const float*)d_in[5];
    float* out = (float*)d_out;

    int BT = in_sizes[2];                   // B*T
    int HALF = BT / 2;                      // each thread covers idx and idx+HALF
    int nwaves = (HALF + 59) / 60;          // 60 outputs per wave
    int blocks = (nwaves + 3) / 4;          // 4 waves per 256-thread block
    hipLaunchKernelGGL(nstep_qloss_kernel, dim3(blocks), dim3(256), 0, stream,
                       cur_q, next_q, log_p, reward, is_done, mask, out, HALF);
}